// Round 1
// baseline (562.595 us; speedup 1.0000x reference)
//
#include <hip/hip_runtime.h>
#include <hip/hip_bf16.h>
#include <stdint.h>

// Problem constants (from reference)
#define B_   2
#define S_   4096
#define H_   2048
#define NH_  8
#define D_   128
#define KD_  1024
#define MR   (B_ * S_)          // 8192 rows
#define NQKVZ 4096              // q|k|v|z concatenated width

typedef __attribute__((ext_vector_type(8))) short bf16x8;   // 8 bf16 in 4 VGPRs
typedef __attribute__((ext_vector_type(4))) float f32x4;

__device__ __forceinline__ short f2bf(float f) {
    union { float f; uint32_t u; } v; v.f = f;
    uint32_t r = v.u + 0x7FFF + ((v.u >> 16) & 1);   // RNE
    return (short)(r >> 16);
}

__device__ __forceinline__ void async_ld16(const void* g, void* l) {
    __builtin_amdgcn_global_load_lds(
        (const __attribute__((address_space(1))) uint32_t*)g,
        (__attribute__((address_space(3))) uint32_t*)l, 16, 0, 0);
}

// ---------------- f32 -> bf16 convert (vectorized) ----------------
__global__ __launch_bounds__(256) void k_cvt_bf16(const float* __restrict__ src,
                                                  short* __restrict__ dst, int n4) {
    int i = blockIdx.x * 256 + threadIdx.x;
    if (i >= n4) return;
    float4 v = ((const float4*)src)[i];
    short4 o;
    o.x = f2bf(v.x); o.y = f2bf(v.y); o.z = f2bf(v.z); o.w = f2bf(v.w);
    ((short4*)dst)[i] = o;
}

// ---------------- transpose + convert: W (KxN f32) -> Wt (NxK bf16) ----------------
__global__ __launch_bounds__(256) void k_transpose_cvt(const float* __restrict__ W,
                                                       short* __restrict__ Wt,
                                                       int K, int N) {
    __shared__ float tile[32][33];
    int n0 = blockIdx.x * 32, k0 = blockIdx.y * 32;
    int tx = threadIdx.x, ty = threadIdx.y;   // 32 x 8
#pragma unroll
    for (int i = 0; i < 32; i += 8)
        tile[ty + i][tx] = W[(size_t)(k0 + ty + i) * N + n0 + tx];
    __syncthreads();
#pragma unroll
    for (int i = 0; i < 32; i += 8)
        Wt[(size_t)(n0 + ty + i) * K + k0 + tx] = f2bf(tile[tx][ty + i]);
}

// ---------------- MFMA GEMM: C(MxN f32) = A(MxK bf16) * Bt(NxK bf16)^T ----------------
// m97-style: 128x128 tile, BK=32, 4 waves (2x2), each wave 64x64 = 4x4 MFMA tiles.
__global__ __launch_bounds__(256) void k_gemm(const short* __restrict__ A,
                                              const short* __restrict__ Bt,
                                              float* __restrict__ C,
                                              int M, int N, int K) {
    __shared__ __align__(16) short Als[128 * 32];
    __shared__ __align__(16) short Bls[128 * 32];
    const int t = threadIdx.x;
    const int wave = t >> 6, lane = t & 63;
    const int bm = blockIdx.x * 128, bn = blockIdx.y * 128;
    const int wm = (wave >> 1) * 64, wn = (wave & 1) * 64;

    // staging chunks: 512 chunks of 16B per tile; thread handles c and c+256
    const int c0 = t, c1 = t + 256;
    const int r0 = c0 >> 2, kc0 = (c0 & 3) * 8;
    const int r1 = c1 >> 2, kc1 = (c1 & 3) * 8;
    const short* Ab = A + (size_t)bm * K;
    const short* Bb = Bt + (size_t)bn * K;

    f32x4 acc[4][4] = {};
    const int mrow = lane & 15;
    const int kq = (lane >> 4) * 8;

    for (int k0 = 0; k0 < K; k0 += 32) {
        async_ld16(Ab + (size_t)r0 * K + k0 + kc0, (char*)Als + c0 * 16);
        async_ld16(Ab + (size_t)r1 * K + k0 + kc1, (char*)Als + c1 * 16);
        async_ld16(Bb + (size_t)r0 * K + k0 + kc0, (char*)Bls + c0 * 16);
        async_ld16(Bb + (size_t)r1 * K + k0 + kc1, (char*)Bls + c1 * 16);
        __syncthreads();   // compiler emits s_waitcnt vmcnt(0) before s_barrier
        bf16x8 af[4], bf[4];
#pragma unroll
        for (int i = 0; i < 4; i++) {
            af[i] = *(const bf16x8*)(Als + (wm + i * 16 + mrow) * 32 + kq);
            bf[i] = *(const bf16x8*)(Bls + (wn + i * 16 + mrow) * 32 + kq);
        }
        __syncthreads();   // frags in regs before next-iter staging overwrites LDS
#pragma unroll
        for (int i = 0; i < 4; i++)
#pragma unroll
            for (int j = 0; j < 4; j++)
                acc[i][j] = __builtin_amdgcn_mfma_f32_16x16x32_bf16(af[i], bf[j], acc[i][j], 0, 0, 0);
    }

    // C/D layout (verified m89/m91): col = lane&15, row = (lane>>4)*4 + reg
    const int crow = (lane >> 4) * 4, ccol = lane & 15;
#pragma unroll
    for (int i = 0; i < 4; i++)
#pragma unroll
        for (int j = 0; j < 4; j++) {
            size_t base = (size_t)(bm + wm + i * 16 + crow) * N + (bn + wn + j * 16 + ccol);
#pragma unroll
            for (int r = 0; r < 4; r++)
                C[base + (size_t)r * N] = acc[i][j][r];
        }
}

// ---------------- bg/ag: x(8192x2048) @ [W_b|W_a](2048x8 each) -> bgag(8192x16) ----------------
__global__ __launch_bounds__(256) void k_bgag(const float* __restrict__ x,
                                              const float* __restrict__ Wb,
                                              const float* __restrict__ Wa,
                                              float* __restrict__ bgag) {
    const int m = blockIdx.x, t = threadIdx.x;
    __shared__ float xs[2048];
    __shared__ float part[256];
    const float* xr = x + (size_t)m * H_;
    for (int i = t; i < H_; i += 256) xs[i] = xr[i];
    __syncthreads();
    int col = t & 15, seg = t >> 4;
    const float* W = (col < 8) ? Wb : Wa;
    int c = col & 7;
    float acc = 0.f;
    int kb = seg * 128;
    for (int k = 0; k < 128; k++) acc += xs[kb + k] * W[(size_t)(kb + k) * 8 + c];
    part[t] = acc;
    __syncthreads();
    if (t < 16) {
        float s = 0.f;
        for (int j = 0; j < 16; j++) s += part[j * 16 + t];
        bgag[(size_t)m * 16 + t] = s;   // [0..8)=bg, [8..16)=ag
    }
}

// ---------------- RoPE in-place on q,k sections of qkvz ----------------
__global__ __launch_bounds__(256) void k_rope(float* __restrict__ qkvz) {
    int idx = blockIdx.x * 256 + threadIdx.x;     // MR*NH*64
    int i = idx & 63;
    int h = (idx >> 6) & 7;
    int m = idx >> 9;
    int s = m & (S_ - 1);
    // inv_freq = base^(-2i/D); log2(1e6) = 19.931568569324174
    float ex = -(float)i * (2.0f / 128.0f) * 19.931568569324174f;
    float inv = exp2f(ex);
    float f = (float)s * inv;
    float sn, cs;
    sincosf(f, &sn, &cs);
    float* p = qkvz + (size_t)m * NQKVZ + h * 128 + 2 * i;
    float2 q = *(float2*)p;
    float2 k = *(float2*)(p + 1024);
    float2 qo = { q.x * cs - q.y * sn, q.x * sn + q.y * cs };
    float2 ko = { k.x * cs - k.y * sn, k.x * sn + k.y * cs };
    *(float2*)p = qo;
    *(float2*)(p + 1024) = ko;
}

// ---------------- sliding-window attention + gate + silu(z) + RMSNorm -> yn bf16 ----------------
__global__ __launch_bounds__(256) void k_attn(const float* __restrict__ qkvz,
                                              const float* __restrict__ bgag,
                                              const float* __restrict__ norm_w,
                                              short* __restrict__ yn) {
    const int m = blockIdx.x;
    const int s = m & (S_ - 1);
    const int t = threadIdx.x;
    const int wave = t >> 6, lane = t & 63;
    __shared__ float sc[NH_][5];
    __shared__ float red[4];
    const float* row = qkvz + (size_t)m * NQKVZ;

    // phase 1: scores for 40 (h,off) pairs, 4 threads each
    if (t < 160) {
        int pair = t >> 2;
        int h = pair / 5, off = pair % 5;
        float acc = 0.f;
        if (s >= off) {
            const float* q = row + h * 128;
            const float* kk = qkvz + (size_t)(m - off) * NQKVZ + 1024 + h * 128;
            int d0 = (t & 3) * 32;
#pragma unroll 8
            for (int d = 0; d < 32; d++) acc += q[d0 + d] * kk[d0 + d];
        }
        acc += __shfl_xor(acc, 1);
        acc += __shfl_xor(acc, 2);
        if ((t & 3) == 0) {
            float val = 0.f;
            if (s >= off) {
                float ag = bgag[(size_t)m * 16 + 8 + h];
                float bg = bgag[(size_t)(m - off) * 16 + h];
                float g = 1.f / (1.f + expf(-ag * bg));
                val = acc * 0.08838834764831845f * g;   // * 1/sqrt(128) * sigmoid(ag*bg)
            }
            sc[h][off] = val;
        }
    }
    __syncthreads();

    // phase 2: out accumulation, silu gating, RMS
    float yv[4], zs[4];
    float ss = 0.f;
#pragma unroll
    for (int j = 0; j < 4; j++) {
        int e = t + j * 256;          // 0..1023
        int h = e >> 7;
        float o;
        if (s == 0) {
            o = row[2048 + e];        // out[:,0] = v4[:,0]
        } else {
            o = 0.f;
#pragma unroll
            for (int off = 0; off <= 4; off++)
                if (s >= off) o += sc[h][off] * qkvz[(size_t)(m - off) * NQKVZ + 2048 + e];
        }
        float z = row[3072 + e];
        float sig = 1.f / (1.f + expf(-z));
        float y = o * sig;
        yv[j] = y; zs[j] = z * sig;
        ss += y * y;
    }
#pragma unroll
    for (int w = 1; w < 64; w <<= 1) ss += __shfl_xor(ss, w);
    if (lane == 0) red[wave] = ss;
    __syncthreads();
    float tot = red[0] + red[1] + red[2] + red[3];
    float rinv = 1.f / sqrtf(tot * (1.0f / 1024.0f) + 1e-6f);
#pragma unroll
    for (int j = 0; j < 4; j++) {
        int e = t + j * 256;
        yn[(size_t)m * KD_ + e] = f2bf(yv[j] * rinv * norm_w[e] * zs[j]);
    }
}

extern "C" void kernel_launch(void* const* d_in, const int* in_sizes, int n_in,
                              void* d_out, int out_size, void* d_ws, size_t ws_size,
                              hipStream_t stream) {
    const float* x      = (const float*)d_in[0];
    const float* W_qkv  = (const float*)d_in[1];
    const float* W_z    = (const float*)d_in[2];
    const float* W_b    = (const float*)d_in[3];
    const float* W_a    = (const float*)d_in[4];
    const float* norm_w = (const float*)d_in[5];
    const float* W_out  = (const float*)d_in[6];
    float* out = (float*)d_out;

    // workspace layout (~197 MB total)
    char* ws = (char*)d_ws;
    short* xb   = (short*)ws; ws += (size_t)MR * H_ * 2;        // 32 MB  bf16 x
    short* Wt1  = (short*)ws; ws += (size_t)NQKVZ * H_ * 2;     // 16 MB  [W_qkv|W_z]^T bf16 (4096 x 2048)
    short* Wt2  = (short*)ws; ws += (size_t)H_ * KD_ * 2;       //  4 MB  W_out^T bf16 (2048 x 1024)
    float* qkvz = (float*)ws; ws += (size_t)MR * NQKVZ * 4;     // 128 MB f32 [q|k|v|z]
    float* bgag = (float*)ws; ws += (size_t)MR * 16 * 4;        // 0.5 MB
    short* yn   = (short*)ws; ws += (size_t)MR * KD_ * 2;       // 16 MB  bf16 normed y

    // 1. convert x -> bf16
    k_cvt_bf16<<<(MR * H_ / 4 + 255) / 256, 256, 0, stream>>>(x, xb, MR * H_ / 4);
    // 2. transpose-convert weights
    k_transpose_cvt<<<dim3(3072 / 32, 2048 / 32), dim3(32, 8), 0, stream>>>(W_qkv, Wt1, 2048, 3072);
    k_transpose_cvt<<<dim3(1024 / 32, 2048 / 32), dim3(32, 8), 0, stream>>>(W_z, Wt1 + (size_t)3072 * 2048, 2048, 1024);
    k_transpose_cvt<<<dim3(2048 / 32, 1024 / 32), dim3(32, 8), 0, stream>>>(W_out, Wt2, 1024, 2048);
    // 3. GEMM1: qkvz = x @ [W_qkv|W_z]
    k_gemm<<<dim3(MR / 128, NQKVZ / 128), 256, 0, stream>>>(xb, Wt1, qkvz, MR, NQKVZ, H_);
    // 4. bg/ag skinny GEMM
    k_bgag<<<MR, 256, 0, stream>>>(x, W_b, W_a, bgag);
    // 5. RoPE on q,k
    k_rope<<<MR * NH_ * 64 / 256, 256, 0, stream>>>(qkvz);
    // 6. attention window + gating + RMSNorm -> yn (bf16)
    k_attn<<<MR, 256, 0, stream>>>(qkvz, bgag, norm_w, yn);
    // 7. GEMM2: out = yn @ W_out
    k_gemm<<<dim3(MR / 128, H_ / 128), 256, 0, stream>>>(yn, Wt2, out, MR, H_, KD_);
}

// Round 4
// 528.694 us; speedup vs baseline: 1.0641x; 1.0641x over previous
//
#include <hip/hip_runtime.h>
#include <hip/hip_bf16.h>
#include <stdint.h>

#define B_   2
#define S_   4096
#define H_   2048
#define NH_  8
#define D_   128
#define KD_  1024
#define MR   (B_ * S_)          // 8192 rows
#define NQKVZ 4096              // q|k|v|z concatenated width

typedef __attribute__((ext_vector_type(8))) short bf16x8;
typedef __attribute__((ext_vector_type(4))) float f32x4;

__device__ __forceinline__ short f2bf(float f) {
    union { float f; uint32_t u; } v; v.f = f;
    uint32_t r = v.u + 0x7FFF + ((v.u >> 16) & 1);   // RNE
    return (short)(r >> 16);
}
__device__ __forceinline__ float bf2f(unsigned short u) {
    union { uint32_t u; float f; } v; v.u = (uint32_t)u << 16; return v.f;
}

__device__ __forceinline__ void async_ld16(const void* g, void* l) {
    __builtin_amdgcn_global_load_lds(
        (const __attribute__((address_space(1))) uint32_t*)g,
        (__attribute__((address_space(3))) uint32_t*)l, 16, 0, 0);
}

// ---------------- f32 -> bf16 convert (vectorized) ----------------
__global__ __launch_bounds__(256) void k_cvt_bf16(const float* __restrict__ src,
                                                  short* __restrict__ dst, int n4) {
    int i = blockIdx.x * 256 + threadIdx.x;
    if (i >= n4) return;
    float4 v = ((const float4*)src)[i];
    short4 o;
    o.x = f2bf(v.x); o.y = f2bf(v.y); o.z = f2bf(v.z); o.w = f2bf(v.w);
    ((short4*)dst)[i] = o;
}

// ---------------- transpose + convert: W (KxN f32) -> Wt (NxK bf16) ----------------
__global__ __launch_bounds__(256) void k_transpose_cvt(const float* __restrict__ W,
                                                       short* __restrict__ Wt,
                                                       int K, int N) {
    __shared__ float tile[32][33];
    int n0 = blockIdx.x * 32, k0 = blockIdx.y * 32;
    int tx = threadIdx.x, ty = threadIdx.y;   // 32 x 8
#pragma unroll
    for (int i = 0; i < 32; i += 8)
        tile[ty + i][tx] = W[(size_t)(k0 + ty + i) * N + n0 + tx];
    __syncthreads();
#pragma unroll
    for (int i = 0; i < 32; i += 8)
        Wt[(size_t)(n0 + ty + i) * K + k0 + tx] = f2bf(tile[tx][ty + i]);
}

// ---------------- RoPE table: ctab[s][i] = {cos(s*inv_i), sin(s*inv_i)} ----------------
__global__ __launch_bounds__(256) void k_ropetab(float2* __restrict__ ctab) {
    int idx = blockIdx.x * 256 + threadIdx.x;   // S_*64
    int i = idx & 63, s = idx >> 6;
    // inv = base^(-2i/D); log2(1e6)=19.931568569324174
    float inv = exp2f(-(float)i * (2.0f / 128.0f) * 19.931568569324174f);
    float f = (float)s * inv;
    float sn, cs;
    sincosf(f, &sn, &cs);
    ctab[idx] = make_float2(cs, sn);
}

// ---------------- MFMA GEMM: C = A(MxK bf16) * Bt(NxK bf16)^T ----------------
// EPI=0: store f32 C. EPI=1: fused RoPE on cols<2048, store bf16 C.
template <int EPI>
__global__ __launch_bounds__(256) void k_gemm_t(const short* __restrict__ A,
                                                const short* __restrict__ Bt,
                                                float* __restrict__ Cf,
                                                unsigned short* __restrict__ Cb,
                                                const float2* __restrict__ ctab,
                                                int M, int N, int K) {
    __shared__ __align__(16) short Als[128 * 32];
    __shared__ __align__(16) short Bls[128 * 32];
    const int t = threadIdx.x;
    const int wave = t >> 6, lane = t & 63;
    const int bm = blockIdx.x * 128, bn = blockIdx.y * 128;
    const int wm = (wave >> 1) * 64, wn = (wave & 1) * 64;

    const int c0 = t, c1 = t + 256;
    const int r0 = c0 >> 2, kc0 = (c0 & 3) * 8;
    const int r1 = c1 >> 2, kc1 = (c1 & 3) * 8;
    const short* Ab = A + (size_t)bm * K;
    const short* Bb = Bt + (size_t)bn * K;

    f32x4 acc[4][4] = {};
    const int mrow = lane & 15;
    const int kq = (lane >> 4) * 8;

    for (int k0 = 0; k0 < K; k0 += 32) {
        async_ld16(Ab + (size_t)r0 * K + k0 + kc0, (char*)Als + c0 * 16);
        async_ld16(Ab + (size_t)r1 * K + k0 + kc1, (char*)Als + c1 * 16);
        async_ld16(Bb + (size_t)r0 * K + k0 + kc0, (char*)Bls + c0 * 16);
        async_ld16(Bb + (size_t)r1 * K + k0 + kc1, (char*)Bls + c1 * 16);
        __syncthreads();
        bf16x8 af[4], bf[4];
#pragma unroll
        for (int i = 0; i < 4; i++) {
            af[i] = *(const bf16x8*)(Als + (wm + i * 16 + mrow) * 32 + kq);
            bf[i] = *(const bf16x8*)(Bls + (wn + i * 16 + mrow) * 32 + kq);
        }
        __syncthreads();
#pragma unroll
        for (int i = 0; i < 4; i++)
#pragma unroll
            for (int j = 0; j < 4; j++)
                acc[i][j] = __builtin_amdgcn_mfma_f32_16x16x32_bf16(af[i], bf[j], acc[i][j], 0, 0, 0);
    }

    // C/D layout (verified): col = lane&15, row = (lane>>4)*4 + reg
    const int crow = (lane >> 4) * 4, ccol = lane & 15;
#pragma unroll
    for (int i = 0; i < 4; i++)
#pragma unroll
        for (int j = 0; j < 4; j++) {
            const int col = bn + wn + j * 16 + ccol;
            const int rowb = bm + wm + i * 16 + crow;
            size_t base = (size_t)rowb * N + col;
            if (EPI == 0) {
#pragma unroll
                for (int r = 0; r < 4; r++)
                    Cf[base + (size_t)r * N] = acc[i][j][r];
            } else {
                // cols [0,2048) are q|k: apply RoPE. 16-col tile never straddles
                // the 2048 boundary or a 128 head boundary -> wave-uniform branch.
                const bool qk = col < 2048;
                const int fi = (col & 127) >> 1;
                const bool even = (col & 1) == 0;
#pragma unroll
                for (int r = 0; r < 4; r++) {
                    float v = acc[i][j][r];
                    if (qk) {
                        int s = (rowb + r) & (S_ - 1);
                        float2 cs = ctab[s * 64 + fi];
                        float p = __shfl_xor(v, 1);   // partner col (lane^1 holds same row)
                        // even (x0): o0 = x0*c - x1*s ; odd (x1): o1 = x1*c + x0*s
                        v = even ? v * cs.x - p * cs.y : v * cs.x + p * cs.y;
                    }
                    Cb[base + (size_t)r * N] = (unsigned short)f2bf(v);
                }
            }
        }
}

// ---------------- bg/ag: x(8192x2048) @ [W_b|W_a] -> bgag(8192x16) f32 ----------------
__global__ __launch_bounds__(256) void k_bgag(const float* __restrict__ x,
                                              const float* __restrict__ Wb,
                                              const float* __restrict__ Wa,
                                              float* __restrict__ bgag) {
    const int m = blockIdx.x, t = threadIdx.x;
    __shared__ float xs[2048];
    __shared__ float part[256];
    const float4* xr = (const float4*)(x + (size_t)m * H_);
    ((float4*)xs)[t] = xr[t];
    ((float4*)xs)[t + 256] = xr[t + 256];
    __syncthreads();
    int col = t & 15, seg = t >> 4;
    const float* W = (col < 8) ? Wb : Wa;
    int c = col & 7;
    float acc = 0.f;
    int kb = seg * 128;
    for (int k = 0; k < 128; k++) acc += xs[kb + k] * W[(size_t)(kb + k) * 8 + c];
    part[t] = acc;
    __syncthreads();
    if (t < 16) {
        float s = 0.f;
        for (int j = 0; j < 16; j++) s += part[j * 16 + t];
        bgag[(size_t)m * 16 + t] = s;   // [0..8)=bg, [8..16)=ag
    }
}

// ---------------- sliding-window attn + gate + silu(z) + RMSNorm -> yn bf16 ----------------
__global__ __launch_bounds__(256) void k_attn(const unsigned short* __restrict__ qkvz,
                                              const float* __restrict__ bgag,
                                              const float* __restrict__ norm_w,
                                              short* __restrict__ yn) {
    const int m = blockIdx.x;
    const int s = m & (S_ - 1);
    const int t = threadIdx.x;
    __shared__ unsigned short kvls[5][2048];  // rows m-off, cols [1024,3072) = k|v
    __shared__ unsigned short qzls[2048];     // [0,1024)=q row m, [1024,2048)=z row m
    __shared__ float sc[NH_][5];
    __shared__ float red[4];
    const int nOff = (s < 4 ? s : 4) + 1;

    // stage: coalesced ushort4 loads
    for (int off = 0; off < 5; off++) {
        if (off < nOff) {
            const ushort4* r = (const ushort4*)(qkvz + (size_t)(m - off) * NQKVZ + 1024);
            ushort4* d = (ushort4*)kvls[off];
            d[t] = r[t];
            d[t + 256] = r[t + 256];
        }
    }
    {
        const unsigned short* r = qkvz + (size_t)m * NQKVZ;
        ushort4* d = (ushort4*)qzls;
        d[t] = ((const ushort4*)r)[t];                    // q
        d[256 + t] = ((const ushort4*)(r + 3072))[t];     // z
    }
    __syncthreads();

    // scores: 8 heads x 32 lanes each; each lane covers 4 d's
    {
        const int h = t >> 5, l = t & 31;
        float qv[4];
#pragma unroll
        for (int d = 0; d < 4; d++) qv[d] = bf2f(qzls[h * 128 + l * 4 + d]);
        const float ag = bgag[(size_t)m * 16 + 8 + h];
#pragma unroll
        for (int off = 0; off < 5; off++) {
            float acc = 0.f;
            if (off < nOff) {
#pragma unroll
                for (int d = 0; d < 4; d++)
                    acc += qv[d] * bf2f(kvls[off][h * 128 + l * 4 + d]);
            }
#pragma unroll
            for (int w = 1; w < 32; w <<= 1) acc += __shfl_xor(acc, w);
            if (l == 0) {
                float val = 0.f;
                if (off < nOff) {
                    float bg = bgag[(size_t)(m - off) * 16 + h];
                    float g = 1.f / (1.f + expf(-ag * bg));
                    val = acc * 0.08838834764831845f * g;   // 1/sqrt(128) * gate
                }
                sc[h][off] = val;
            }
        }
    }
    __syncthreads();

    // phase 2: 4 consecutive elements per thread
    const int e0 = t * 4, h = e0 >> 7;
    float o[4] = {0.f, 0.f, 0.f, 0.f};
    if (s == 0) {
#pragma unroll
        for (int d = 0; d < 4; d++) o[d] = bf2f(kvls[0][1024 + e0 + d]);
    } else {
        for (int off = 0; off < nOff; off++) {
            float w = sc[h][off];
#pragma unroll
            for (int d = 0; d < 4; d++) o[d] += w * bf2f(kvls[off][1024 + e0 + d]);
        }
    }
    float y[4], zs4[4], ss = 0.f;
#pragma unroll
    for (int d = 0; d < 4; d++) {
        float z = bf2f(qzls[1024 + e0 + d]);
        float sg = 1.f / (1.f + expf(-z));
        y[d] = o[d] * sg;
        zs4[d] = z * sg;
        ss += y[d] * y[d];
    }
    const int wave = t >> 6, lane = t & 63;
#pragma unroll
    for (int w = 1; w < 64; w <<= 1) ss += __shfl_xor(ss, w);
    if (lane == 0) red[wave] = ss;
    __syncthreads();
    float tot = red[0] + red[1] + red[2] + red[3];
    float rinv = 1.f / sqrtf(tot * (1.0f / 1024.0f) + 1e-6f);
    short4 ov;
    ov.x = f2bf(y[0] * rinv * norm_w[e0 + 0] * zs4[0]);
    ov.y = f2bf(y[1] * rinv * norm_w[e0 + 1] * zs4[1]);
    ov.z = f2bf(y[2] * rinv * norm_w[e0 + 2] * zs4[2]);
    ov.w = f2bf(y[3] * rinv * norm_w[e0 + 3] * zs4[3]);
    ((short4*)yn)[(size_t)m * 256 + t] = ov;
}

extern "C" void kernel_launch(void* const* d_in, const int* in_sizes, int n_in,
                              void* d_out, int out_size, void* d_ws, size_t ws_size,
                              hipStream_t stream) {
    const float* x      = (const float*)d_in[0];
    const float* W_qkv  = (const float*)d_in[1];
    const float* W_z    = (const float*)d_in[2];
    const float* W_b    = (const float*)d_in[3];
    const float* W_a    = (const float*)d_in[4];
    const float* norm_w = (const float*)d_in[5];
    const float* W_out  = (const float*)d_in[6];
    float* out = (float*)d_out;

    // workspace (~135 MB)
    char* ws = (char*)d_ws;
    short* xb    = (short*)ws;          ws += (size_t)MR * H_ * 2;       // 32 MB
    short* Wt1   = (short*)ws;          ws += (size_t)NQKVZ * H_ * 2;    // 16 MB
    short* Wt2   = (short*)ws;          ws += (size_t)H_ * KD_ * 2;      //  4 MB
    unsigned short* qkvzb = (unsigned short*)ws; ws += (size_t)MR * NQKVZ * 2; // 64 MB bf16 q|k|v|z (rope applied)
    float* bgag  = (float*)ws;          ws += (size_t)MR * 16 * 4;       // 0.5 MB
    short* yn    = (short*)ws;          ws += (size_t)MR * KD_ * 2;      // 16 MB
    float2* ctab = (float2*)ws;         ws += (size_t)S_ * 64 * 8;       //  2 MB

    // 1. convert x -> bf16
    k_cvt_bf16<<<(MR * H_ / 4 + 255) / 256, 256, 0, stream>>>(x, xb, MR * H_ / 4);
    // 2. transpose-convert weights
    k_transpose_cvt<<<dim3(3072 / 32, 2048 / 32), dim3(32, 8), 0, stream>>>(W_qkv, Wt1, 2048, 3072);
    k_transpose_cvt<<<dim3(1024 / 32, 2048 / 32), dim3(32, 8), 0, stream>>>(W_z, Wt1 + (size_t)3072 * 2048, 2048, 1024);
    k_transpose_cvt<<<dim3(2048 / 32, 1024 / 32), dim3(32, 8), 0, stream>>>(W_out, Wt2, 1024, 2048);
    // 3. rope table
    k_ropetab<<<S_ * 64 / 256, 256, 0, stream>>>(ctab);
    // 4. GEMM1 (fused rope epilogue, bf16 out): qkvz = rope(x @ [W_qkv|W_z])
    k_gemm_t<1><<<dim3(MR / 128, NQKVZ / 128), 256, 0, stream>>>(xb, Wt1, nullptr, qkvzb, ctab, MR, NQKVZ, H_);
    // 5. bg/ag skinny GEMM
    k_bgag<<<MR, 256, 0, stream>>>(x, W_b, W_a, bgag);
    // 6. attention window + gating + RMSNorm -> yn (bf16)
    k_attn<<<MR, 256, 0, stream>>>(qkvzb, bgag, norm_w, yn);
    // 7. GEMM2: out = yn @ W_out
    k_gemm_t<0><<<dim3(MR / 128, H_ / 128), 256, 0, stream>>>(yn, Wt2, out, nullptr, nullptr, MR, H_, KD_);
}

// Round 5
// 522.431 us; speedup vs baseline: 1.0769x; 1.0120x over previous
//
#include <hip/hip_runtime.h>
#include <hip/hip_bf16.h>
#include <stdint.h>

#define B_   2
#define S_   4096
#define H_   2048
#define NH_  8
#define D_   128
#define KD_  1024
#define MR   (B_ * S_)          // 8192 rows
#define NQKVZ 4096              // q|k|v|z concatenated width

typedef __attribute__((ext_vector_type(8))) short bf16x8;
typedef __attribute__((ext_vector_type(4))) float f32x4;

__device__ __forceinline__ short f2bf(float f) {
    union { float f; uint32_t u; } v; v.f = f;
    uint32_t r = v.u + 0x7FFF + ((v.u >> 16) & 1);   // RNE
    return (short)(r >> 16);
}
__device__ __forceinline__ float bf2f(unsigned short u) {
    union { uint32_t u; float f; } v; v.u = (uint32_t)u << 16; return v.f;
}

__device__ __forceinline__ void async_ld16(const void* g, void* l) {
    __builtin_amdgcn_global_load_lds(
        (const __attribute__((address_space(1))) uint32_t*)g,
        (__attribute__((address_space(3))) uint32_t*)l, 16, 0, 0);
}

// ---------------- fused: x row -> bf16 + bgag skinny GEMM ----------------
__global__ __launch_bounds__(256) void k_cvt_bgag(const float* __restrict__ x,
                                                  short* __restrict__ xb,
                                                  const float* __restrict__ Wb,
                                                  const float* __restrict__ Wa,
                                                  float* __restrict__ bgag) {
    const int m = blockIdx.x, t = threadIdx.x;
    __shared__ float xs[2048];
    __shared__ float part[256];
    const float4* xr = (const float4*)(x + (size_t)m * H_);
    float4 a = xr[t], b = xr[t + 256];
    ((float4*)xs)[t] = a;
    ((float4*)xs)[t + 256] = b;
    short4 oa, ob;
    oa.x = f2bf(a.x); oa.y = f2bf(a.y); oa.z = f2bf(a.z); oa.w = f2bf(a.w);
    ob.x = f2bf(b.x); ob.y = f2bf(b.y); ob.z = f2bf(b.z); ob.w = f2bf(b.w);
    short4* xo = (short4*)(xb + (size_t)m * H_);
    xo[t] = oa;
    xo[t + 256] = ob;
    __syncthreads();
    int col = t & 15, seg = t >> 4;
    const float* W = (col < 8) ? Wb : Wa;
    int c = col & 7;
    float acc = 0.f;
    int kb = seg * 128;
    for (int k = 0; k < 128; k++) acc += xs[kb + k] * W[(size_t)(kb + k) * 8 + c];
    part[t] = acc;
    __syncthreads();
    if (t < 16) {
        float s = 0.f;
        for (int j = 0; j < 16; j++) s += part[j * 16 + t];
        bgag[(size_t)m * 16 + t] = s;   // [0..8)=bg, [8..16)=ag
    }
}

// ---------------- transpose + convert: W (KxN f32) -> Wt (NxK bf16) ----------------
__global__ __launch_bounds__(256) void k_transpose_cvt(const float* __restrict__ W,
                                                       short* __restrict__ Wt,
                                                       int K, int N) {
    __shared__ float tile[32][33];
    int n0 = blockIdx.x * 32, k0 = blockIdx.y * 32;
    int tx = threadIdx.x, ty = threadIdx.y;   // 32 x 8
#pragma unroll
    for (int i = 0; i < 32; i += 8)
        tile[ty + i][tx] = W[(size_t)(k0 + ty + i) * N + n0 + tx];
    __syncthreads();
#pragma unroll
    for (int i = 0; i < 32; i += 8)
        Wt[(size_t)(n0 + ty + i) * K + k0 + tx] = f2bf(tile[tx][ty + i]);
}

// ---------------- RoPE table: ctab[s][i] = {cos(s*inv_i), sin(s*inv_i)} ----------------
__global__ __launch_bounds__(256) void k_ropetab(float2* __restrict__ ctab) {
    int idx = blockIdx.x * 256 + threadIdx.x;   // S_*64
    int i = idx & 63, s = idx >> 6;
    float inv = exp2f(-(float)i * (2.0f / 128.0f) * 19.931568569324174f);
    float f = (float)s * inv;
    float sn, cs;
    sincosf(f, &sn, &cs);
    ctab[idx] = make_float2(cs, sn);
}

// ---------------- MFMA GEMM: C = A(MxK bf16) * Bt(NxK bf16)^T ----------------
// EPI=0: store f32 C. EPI=1: fused RoPE on cols<2048, packed-dword bf16 stores.
template <int EPI>
__global__ __launch_bounds__(256) void k_gemm_t(const short* __restrict__ A,
                                                const short* __restrict__ Bt,
                                                float* __restrict__ Cf,
                                                unsigned short* __restrict__ Cb,
                                                const float2* __restrict__ ctab,
                                                int M, int N, int K) {
    __shared__ __align__(16) short Als[128 * 32];
    __shared__ __align__(16) short Bls[128 * 32];
    const int t = threadIdx.x;
    const int wave = t >> 6, lane = t & 63;
    const int bm = blockIdx.x * 128, bn = blockIdx.y * 128;
    const int wm = (wave >> 1) * 64, wn = (wave & 1) * 64;

    const int c0 = t, c1 = t + 256;
    const int r0 = c0 >> 2, kc0 = (c0 & 3) * 8;
    const int r1 = c1 >> 2, kc1 = (c1 & 3) * 8;
    const short* Ab = A + (size_t)bm * K;
    const short* Bb = Bt + (size_t)bn * K;

    f32x4 acc[4][4] = {};
    const int mrow = lane & 15;
    const int kq = (lane >> 4) * 8;

    for (int k0 = 0; k0 < K; k0 += 32) {
        async_ld16(Ab + (size_t)r0 * K + k0 + kc0, (char*)Als + c0 * 16);
        async_ld16(Ab + (size_t)r1 * K + k0 + kc1, (char*)Als + c1 * 16);
        async_ld16(Bb + (size_t)r0 * K + k0 + kc0, (char*)Bls + c0 * 16);
        async_ld16(Bb + (size_t)r1 * K + k0 + kc1, (char*)Bls + c1 * 16);
        __syncthreads();
        bf16x8 af[4], bf[4];
#pragma unroll
        for (int i = 0; i < 4; i++) {
            af[i] = *(const bf16x8*)(Als + (wm + i * 16 + mrow) * 32 + kq);
            bf[i] = *(const bf16x8*)(Bls + (wn + i * 16 + mrow) * 32 + kq);
        }
        __syncthreads();
#pragma unroll
        for (int i = 0; i < 4; i++)
#pragma unroll
            for (int j = 0; j < 4; j++)
                acc[i][j] = __builtin_amdgcn_mfma_f32_16x16x32_bf16(af[i], bf[j], acc[i][j], 0, 0, 0);
    }

    // C/D layout (verified): col = lane&15, row = (lane>>4)*4 + reg
    const int crow = (lane >> 4) * 4, ccol = lane & 15;
#pragma unroll
    for (int i = 0; i < 4; i++)
#pragma unroll
        for (int j = 0; j < 4; j++) {
            const int col = bn + wn + j * 16 + ccol;
            const int rowb = bm + wm + i * 16 + crow;
            size_t base = (size_t)rowb * N + col;
            if (EPI == 0) {
#pragma unroll
                for (int r = 0; r < 4; r++)
                    Cf[base + (size_t)r * N] = acc[i][j][r];
            } else {
                // cols [0,2048) are q|k: apply RoPE. 16-col tile never straddles
                // the 2048 boundary or a 128 head boundary -> wave-uniform branch.
                const bool qk = col < 2048;
                const int fi = (col & 127) >> 1;
                const bool even = (col & 1) == 0;
                // lane^1 holds the partner column of the same rows: pack 2 bf16
                // per dword, even lanes store (half the store instrs of r4).
                uint32_t* Cd = (uint32_t*)(Cb + ((size_t)rowb * N + (col & ~1)));
#pragma unroll
                for (int r = 0; r < 4; r++) {
                    float v = acc[i][j][r];
                    if (qk) {
                        int s = (rowb + r) & (S_ - 1);
                        float2 cs = ctab[s * 64 + fi];
                        float p = __shfl_xor(v, 1);
                        // even (x0): o0 = x0*c - x1*s ; odd (x1): o1 = x1*c + x0*s
                        v = even ? v * cs.x - p * cs.y : v * cs.x + p * cs.y;
                    }
                    int hb = (int)(unsigned short)f2bf(v);
                    int pb = __shfl_xor(hb, 1);
                    if (even)
                        Cd[(size_t)r * (N >> 1)] = (uint32_t)(hb | (pb << 16));
                }
            }
        }
}

// ---------------- sliding-window attn + gate + silu(z) + RMSNorm -> yn bf16 ----------------
__global__ __launch_bounds__(256) void k_attn(const unsigned short* __restrict__ qkvz,
                                              const float* __restrict__ bgag,
                                              const float* __restrict__ norm_w,
                                              short* __restrict__ yn) {
    const int m = blockIdx.x;
    const int s = m & (S_ - 1);
    const int t = threadIdx.x;
    __shared__ unsigned short kvls[5][2048];  // rows m-off, cols [1024,3072) = k|v
    __shared__ unsigned short qzls[2048];     // [0,1024)=q row m, [1024,2048)=z row m
    __shared__ float sc[NH_][5];
    __shared__ float red[4];
    const int nOff = (s < 4 ? s : 4) + 1;

    for (int off = 0; off < 5; off++) {
        if (off < nOff) {
            const ushort4* r = (const ushort4*)(qkvz + (size_t)(m - off) * NQKVZ + 1024);
            ushort4* d = (ushort4*)kvls[off];
            d[t] = r[t];
            d[t + 256] = r[t + 256];
        }
    }
    {
        const unsigned short* r = qkvz + (size_t)m * NQKVZ;
        ushort4* d = (ushort4*)qzls;
        d[t] = ((const ushort4*)r)[t];                    // q
        d[256 + t] = ((const ushort4*)(r + 3072))[t];     // z
    }
    __syncthreads();

    // scores: 8 heads x 32 lanes each; each lane covers 4 d's
    {
        const int h = t >> 5, l = t & 31;
        float qv[4];
#pragma unroll
        for (int d = 0; d < 4; d++) qv[d] = bf2f(qzls[h * 128 + l * 4 + d]);
        const float ag = bgag[(size_t)m * 16 + 8 + h];
#pragma unroll
        for (int off = 0; off < 5; off++) {
            float acc = 0.f;
            if (off < nOff) {
#pragma unroll
                for (int d = 0; d < 4; d++)
                    acc += qv[d] * bf2f(kvls[off][h * 128 + l * 4 + d]);
            }
#pragma unroll
            for (int w = 1; w < 32; w <<= 1) acc += __shfl_xor(acc, w);
            if (l == 0) {
                float val = 0.f;
                if (off < nOff) {
                    float bg = bgag[(size_t)(m - off) * 16 + h];
                    float g = 1.f / (1.f + expf(-ag * bg));
                    val = acc * 0.08838834764831845f * g;   // 1/sqrt(128) * gate
                }
                sc[h][off] = val;
            }
        }
    }
    __syncthreads();

    // phase 2: 4 consecutive elements per thread
    const int e0 = t * 4, h = e0 >> 7;
    float o[4] = {0.f, 0.f, 0.f, 0.f};
    if (s == 0) {
#pragma unroll
        for (int d = 0; d < 4; d++) o[d] = bf2f(kvls[0][1024 + e0 + d]);
    } else {
        for (int off = 0; off < nOff; off++) {
            float w = sc[h][off];
#pragma unroll
            for (int d = 0; d < 4; d++) o[d] += w * bf2f(kvls[off][1024 + e0 + d]);
        }
    }
    float y[4], zs4[4], ss = 0.f;
#pragma unroll
    for (int d = 0; d < 4; d++) {
        float z = bf2f(qzls[1024 + e0 + d]);
        float sg = 1.f / (1.f + expf(-z));
        y[d] = o[d] * sg;
        zs4[d] = z * sg;
        ss += y[d] * y[d];
    }
    const int wave = t >> 6, lane = t & 63;
#pragma unroll
    for (int w = 1; w < 64; w <<= 1) ss += __shfl_xor(ss, w);
    if (lane == 0) red[wave] = ss;
    __syncthreads();
    float tot = red[0] + red[1] + red[2] + red[3];
    float rinv = 1.f / sqrtf(tot * (1.0f / 1024.0f) + 1e-6f);
    short4 ov;
    ov.x = f2bf(y[0] * rinv * norm_w[e0 + 0] * zs4[0]);
    ov.y = f2bf(y[1] * rinv * norm_w[e0 + 1] * zs4[1]);
    ov.z = f2bf(y[2] * rinv * norm_w[e0 + 2] * zs4[2]);
    ov.w = f2bf(y[3] * rinv * norm_w[e0 + 3] * zs4[3]);
    ((short4*)yn)[(size_t)m * 256 + t] = ov;
}

extern "C" void kernel_launch(void* const* d_in, const int* in_sizes, int n_in,
                              void* d_out, int out_size, void* d_ws, size_t ws_size,
                              hipStream_t stream) {
    const float* x      = (const float*)d_in[0];
    const float* W_qkv  = (const float*)d_in[1];
    const float* W_z    = (const float*)d_in[2];
    const float* W_b    = (const float*)d_in[3];
    const float* W_a    = (const float*)d_in[4];
    const float* norm_w = (const float*)d_in[5];
    const float* W_out  = (const float*)d_in[6];
    float* out = (float*)d_out;

    // workspace (~135 MB)
    char* ws = (char*)d_ws;
    short* xb    = (short*)ws;          ws += (size_t)MR * H_ * 2;       // 32 MB
    short* Wt1   = (short*)ws;          ws += (size_t)NQKVZ * H_ * 2;    // 16 MB
    short* Wt2   = (short*)ws;          ws += (size_t)H_ * KD_ * 2;      //  4 MB
    unsigned short* qkvzb = (unsigned short*)ws; ws += (size_t)MR * NQKVZ * 2; // 64 MB
    float* bgag  = (float*)ws;          ws += (size_t)MR * 16 * 4;       // 0.5 MB
    short* yn    = (short*)ws;          ws += (size_t)MR * KD_ * 2;      // 16 MB
    float2* ctab = (float2*)ws;         ws += (size_t)S_ * 64 * 8;       //  2 MB

    // 1. fused convert x->bf16 + bg/ag skinny GEMM (single pass over x)
    k_cvt_bgag<<<MR, 256, 0, stream>>>(x, xb, W_b, W_a, bgag);
    // 2. transpose-convert weights
    k_transpose_cvt<<<dim3(3072 / 32, 2048 / 32), dim3(32, 8), 0, stream>>>(W_qkv, Wt1, 2048, 3072);
    k_transpose_cvt<<<dim3(1024 / 32, 2048 / 32), dim3(32, 8), 0, stream>>>(W_z, Wt1 + (size_t)3072 * 2048, 2048, 1024);
    k_transpose_cvt<<<dim3(2048 / 32, 1024 / 32), dim3(32, 8), 0, stream>>>(W_out, Wt2, 1024, 2048);
    // 3. rope table
    k_ropetab<<<S_ * 64 / 256, 256, 0, stream>>>(ctab);
    // 4. GEMM1 (fused rope epilogue, packed bf16 out): qkvz = rope(x @ [W_qkv|W_z])
    k_gemm_t<1><<<dim3(MR / 128, NQKVZ / 128), 256, 0, stream>>>(xb, Wt1, nullptr, qkvzb, ctab, MR, NQKVZ, H_);
    // 5. attention window + gating + RMSNorm -> yn (bf16)
    k_attn<<<MR, 256, 0, stream>>>(qkvzb, bgag, norm_w, yn);
    // 6. GEMM2: out = yn @ W_out
    k_gemm_t<0><<<dim3(MR / 128, H_ / 128), 256, 0, stream>>>(yn, Wt2, out, nullptr, nullptr, MR, H_, KD_);
}